// Round 1
// baseline (117.195 us; speedup 1.0000x reference)
//
#include <hip/hip_runtime.h>

// AggregationRebuild: sim/T -> gather K=8 -> softmax -> weighted sum of
// gathered neighbor feature rows.
// Outputs (concat flat): weights [N,K] f32, rebuild [N,L,D] f32.

constexpr int N = 2048;
constexpr int K = 8;
constexpr int L = 64;
constexpr int D = 64;
constexpr int LD = L * D;              // 4096 floats per row
constexpr float INV_TEMP = 2.0f;       // 1 / 0.5

__global__ __launch_bounds__(256) void agg_rebuild_kernel(
    const float* __restrict__ sim,     // [N, N]
    const float* __restrict__ emb,     // [N, L*D]
    const int*   __restrict__ idx32,   // [N, K] as int32 OR int64 (detected)
    float* __restrict__ w_out,         // [N, K]
    float* __restrict__ rebuild) {     // [N, L*D]
  const int n   = blockIdx.x;
  const int tid = threadIdx.x;

  __shared__ int   nb[K];
  __shared__ float sraw[K];
  __shared__ float wsm[K];
  __shared__ int   is64_s;

  // Detect int64 vs int32 index layout: values are in [0, 2048), so for an
  // int64 little-endian array every odd int32 word is 0. For int32 data the
  // odd entries are random indices — P(all 8 are 0) ~ (1/2048)^8 ~ 0.
  if (tid == 0) {
    int acc = idx32[1] | idx32[3] | idx32[5] | idx32[7] |
              idx32[9] | idx32[11] | idx32[13] | idx32[15];
    is64_s = (acc == 0) ? 1 : 0;
  }
  __syncthreads();
  const bool is64 = (is64_s != 0);

  if (tid < K) {
    const int flat = n * K + tid;
    const int j = is64 ? idx32[2 * flat] : idx32[flat];
    nb[tid]   = j;
    sraw[tid] = sim[(size_t)n * N + j] * INV_TEMP;
  }
  __syncthreads();

  if (tid < K) {
    float m = sraw[0];
#pragma unroll
    for (int k = 1; k < K; ++k) m = fmaxf(m, sraw[k]);
    float sum = 0.0f;
#pragma unroll
    for (int k = 0; k < K; ++k) sum += expf(sraw[k] - m);
    const float wk = expf(sraw[tid] - m) / sum;
    wsm[tid] = wk;
    w_out[n * K + tid] = wk;
  }
  __syncthreads();

  // Per-thread copies of weights + neighbor row base pointers.
  float wr[K];
  const float4* __restrict__ erow[K];
#pragma unroll
  for (int k = 0; k < K; ++k) {
    wr[k]   = wsm[k];
    erow[k] = reinterpret_cast<const float4*>(emb + (size_t)nb[k] * LD);
  }
  float4* __restrict__ out4 = reinterpret_cast<float4*>(rebuild + (size_t)n * LD);

  // LD/4 = 1024 float4 chunks, 256 threads -> 4 chunks per thread.
#pragma unroll
  for (int it = 0; it < LD / 4 / 256; ++it) {
    const int c = tid + it * 256;
    float4 acc = make_float4(0.f, 0.f, 0.f, 0.f);
#pragma unroll
    for (int k = 0; k < K; ++k) {
      const float4 v = erow[k][c];
      acc.x = fmaf(wr[k], v.x, acc.x);
      acc.y = fmaf(wr[k], v.y, acc.y);
      acc.z = fmaf(wr[k], v.z, acc.z);
      acc.w = fmaf(wr[k], v.w, acc.w);
    }
    out4[c] = acc;
  }
}

extern "C" void kernel_launch(void* const* d_in, const int* in_sizes, int n_in,
                              void* d_out, int out_size, void* d_ws, size_t ws_size,
                              hipStream_t stream) {
  const float* sim = (const float*)d_in[0];
  const float* emb = (const float*)d_in[1];
  const int*   idx = (const int*)d_in[2];
  float* out     = (float*)d_out;
  float* w_out   = out;                       // [N, K]
  float* rebuild = out + (size_t)N * K;       // [N, L*D]

  hipLaunchKernelGGL(agg_rebuild_kernel, dim3(N), dim3(256), 0, stream,
                     sim, emb, idx, w_out, rebuild);
}

// Round 3
// 98.940 us; speedup vs baseline: 1.1845x; 1.1845x over previous
//
#include <hip/hip_runtime.h>

// AggregationRebuild: sim/T -> gather K=8 -> softmax -> weighted sum of
// gathered neighbor feature rows.
// Outputs (concat flat): weights [N,K] f32, rebuild [N,L,D] f32.
//
// Two kernels:
//   A (weights): resolve idx (int64/int32 autodetect), gather sim, softmax
//      over K=8 via intra-wave shuffles; write weights to d_out and to ws.
//   B (rebuild): XCD-L2-tiled weighted gather-sum. Column tile = bid % 8
//      (round-robin dispatch puts equal-residue blocks on the same XCD, so
//      each XCD's L2 holds one 4 MB column slice of emb). Non-temporal
//      output stores keep the slice resident.

typedef float f32x4 __attribute__((ext_vector_type(4)));

constexpr int N  = 2048;
constexpr int K  = 8;
constexpr int LD = 64 * 64;            // 4096 floats per row
constexpr float INV_TEMP = 2.0f;       // 1 / 0.5

constexpr int TILE   = 512;            // floats per column tile
constexpr int NTILES = LD / TILE;      // 8 == #XCDs
constexpr int RPB    = 8;              // rows per block in kernel B

// ---------------- Kernel A: indices + softmax weights ----------------
__global__ __launch_bounds__(256) void weights_kernel(
    const float* __restrict__ sim,     // [N, N]
    const int*   __restrict__ idx32,   // [N, K] int32 or int64 (detected)
    float* __restrict__ w_out,         // [N, K] (output section)
    float* __restrict__ w_ws,          // [N, K] scratch
    int*   __restrict__ j_ws) {        // [N, K] scratch (resolved int32)
  const int g = blockIdx.x * 256 + threadIdx.x;
  const int r = g >> 3;
  const int k = g & 7;

  __shared__ int is64_s;
  if (threadIdx.x == 0) {
    int acc = idx32[1] | idx32[3] | idx32[5] | idx32[7] |
              idx32[9] | idx32[11] | idx32[13] | idx32[15];
    is64_s = (acc == 0) ? 1 : 0;
  }
  __syncthreads();

  const int flat = r * K + k;
  const int j = is64_s ? idx32[2 * flat] : idx32[flat];
  const float s = sim[(size_t)r * N + j] * INV_TEMP;

  float m = s;
  m = fmaxf(m, __shfl_xor(m, 1, 8));
  m = fmaxf(m, __shfl_xor(m, 2, 8));
  m = fmaxf(m, __shfl_xor(m, 4, 8));
  const float e = expf(s - m);
  float sum = e;
  sum += __shfl_xor(sum, 1, 8);
  sum += __shfl_xor(sum, 2, 8);
  sum += __shfl_xor(sum, 4, 8);
  const float w = e / sum;

  w_out[flat] = w;
  w_ws[flat]  = w;
  j_ws[flat]  = j;
}

// ---------------- Kernel B: XCD-tiled weighted gather-sum ----------------
__global__ __launch_bounds__(256) void rebuild_kernel(
    const float* __restrict__ emb,     // [N, LD]
    const float* __restrict__ w_ws,    // [N, K]
    const int*   __restrict__ j_ws,    // [N, K]
    float* __restrict__ rebuild) {     // [N, LD]
  const int tile = blockIdx.x & (NTILES - 1);
  const int rg   = blockIdx.x >> 3;    // row group
  const int r0   = rg * RPB;
  const int tid  = threadIdx.x;

  __shared__ float w_lds[RPB][K];
  __shared__ int   j_lds[RPB][K];
  if (tid < RPB * K) {
    w_lds[tid >> 3][tid & 7] = w_ws[r0 * K + tid];
    j_lds[tid >> 3][tid & 7] = j_ws[r0 * K + tid];
  }
  __syncthreads();

  const int c   = tid & 127;           // float4 chunk within tile (128 chunks)
  const int sub = tid >> 7;            // 0..1 : two rows in flight per pass
  const int col = tile * TILE + c * 4;

#pragma unroll
  for (int it = 0; it < RPB / 2; ++it) {
    const int rl = it * 2 + sub;
    float w[K];
    const f32x4* p[K];
#pragma unroll
    for (int k = 0; k < K; ++k) {
      w[k] = w_lds[rl][k];
      p[k] = reinterpret_cast<const f32x4*>(emb + (size_t)j_lds[rl][k] * LD + col);
    }
    f32x4 acc = (f32x4)(0.0f);
#pragma unroll
    for (int k = 0; k < K; ++k) {
      const f32x4 v = *p[k];
      acc += w[k] * v;                  // element-wise fma on native vector
    }
    f32x4* o = reinterpret_cast<f32x4*>(rebuild + (size_t)(r0 + rl) * LD + col);
    __builtin_nontemporal_store(acc, o);
  }
}

extern "C" void kernel_launch(void* const* d_in, const int* in_sizes, int n_in,
                              void* d_out, int out_size, void* d_ws, size_t ws_size,
                              hipStream_t stream) {
  const float* sim = (const float*)d_in[0];
  const float* emb = (const float*)d_in[1];
  const int*   idx = (const int*)d_in[2];
  float* out     = (float*)d_out;
  float* w_out   = out;                       // [N, K]
  float* rebuild = out + (size_t)N * K;       // [N, LD]

  float* w_ws = (float*)d_ws;                 // [N, K]
  int*   j_ws = (int*)(w_ws + (size_t)N * K); // [N, K]

  hipLaunchKernelGGL(weights_kernel, dim3(N * K / 256), dim3(256), 0, stream,
                     sim, idx, w_out, w_ws, j_ws);
  hipLaunchKernelGGL(rebuild_kernel, dim3((N / RPB) * NTILES), dim3(256), 0, stream,
                     emb, w_ws, j_ws, rebuild);
}